// Round 1
// baseline (1112.897 us; speedup 1.0000x reference)
//
#include <hip/hip_runtime.h>

#define N_NODES 100000
#define N_EDGES 1600000
#define IN_F 256
#define OUT_F 32
#define HEADS 4
#define HF 128  // HEADS*OUT_F
#define NEG_SLOPE 0.2f

// ---------------- GEMM: feat_src = feat @ W^T  ([N,256] x [128,256]^T -> [N,128])
#define BN 64
#define BK 32

__global__ __launch_bounds__(256) void gemm_kernel(const float* __restrict__ feat,
                                                   const float* __restrict__ W,
                                                   float* __restrict__ feat_src) {
    __shared__ float fT[BN][36];   // padded: 36*4=144B rows (16B aligned, 2-way banks only)
    __shared__ float wT[HF][36];
    const int t  = threadIdx.x;
    const int tx = t & 15;   // output group: o = tx + 16*j
    const int ty = t >> 4;   // node group:   n = n0 + ty*4 + i
    const int n0 = blockIdx.x * BN;

    float acc[4][8];
#pragma unroll
    for (int i = 0; i < 4; ++i)
#pragma unroll
        for (int j = 0; j < 8; ++j) acc[i][j] = 0.f;

    for (int k0 = 0; k0 < IN_F; k0 += BK) {
        // load feat tile 64x32 (8 floats/thread)
        {
            const int nn = t >> 2, kk = (t & 3) * 8;
            const int n = n0 + nn;
            float4 a, b;
            if (n < N_NODES) {
                const float* p = feat + (size_t)n * IN_F + k0 + kk;
                a = *(const float4*)p;
                b = *(const float4*)(p + 4);
            } else {
                a = make_float4(0.f, 0.f, 0.f, 0.f);
                b = a;
            }
            float* q = &fT[nn][kk];
            *(float4*)q       = a;
            *(float4*)(q + 4) = b;
        }
        // load W tile 128x32 (16 floats/thread)
        {
            const int o = t >> 1, kk = (t & 1) * 16;
            const float* p = W + (size_t)o * IN_F + k0 + kk;
            float4 a = *(const float4*)p;
            float4 b = *(const float4*)(p + 4);
            float4 c = *(const float4*)(p + 8);
            float4 d = *(const float4*)(p + 12);
            float* q = &wT[o][kk];
            ((float4*)q)[0] = a; ((float4*)q)[1] = b;
            ((float4*)q)[2] = c; ((float4*)q)[3] = d;
        }
        __syncthreads();

#pragma unroll
        for (int kk = 0; kk < BK; kk += 4) {
            float4 fv[4], wv[8];
#pragma unroll
            for (int i = 0; i < 4; ++i) fv[i] = *(const float4*)&fT[ty * 4 + i][kk];
#pragma unroll
            for (int j = 0; j < 8; ++j) wv[j] = *(const float4*)&wT[tx + 16 * j][kk];
#pragma unroll
            for (int i = 0; i < 4; ++i)
#pragma unroll
                for (int j = 0; j < 8; ++j) {
                    acc[i][j] += fv[i].x * wv[j].x + fv[i].y * wv[j].y +
                                 fv[i].z * wv[j].z + fv[i].w * wv[j].w;
                }
        }
        __syncthreads();
    }

#pragma unroll
    for (int i = 0; i < 4; ++i) {
        const int n = n0 + ty * 4 + i;
        if (n >= N_NODES) break;
#pragma unroll
        for (int j = 0; j < 8; ++j) feat_src[(size_t)n * HF + tx + 16 * j] = acc[i][j];
    }
}

// ---------------- per-node attention logits el/er
__global__ void elr_kernel(const float* __restrict__ fs,
                           const float* __restrict__ attn_l,
                           const float* __restrict__ attn_r,
                           float* __restrict__ el, float* __restrict__ er) {
    const int tid = blockIdx.x * blockDim.x + threadIdx.x;
    if (tid >= N_NODES * HEADS) return;
    const int h = tid & 3, n = tid >> 2;
    const float* p = fs + (size_t)n * HF + h * OUT_F;
    float sl = 0.f, sr = 0.f;
#pragma unroll
    for (int f = 0; f < OUT_F; f += 4) {
        float4 v  = *(const float4*)(p + f);
        float4 al = *(const float4*)(attn_l + h * OUT_F + f);
        float4 ar = *(const float4*)(attn_r + h * OUT_F + f);
        sl += v.x * al.x + v.y * al.y + v.z * al.z + v.w * al.w;
        sr += v.x * ar.x + v.y * ar.y + v.z * ar.z + v.w * ar.w;
    }
    el[tid] = sl;
    er[tid] = sr;
}

// ---------------- edge logits + LeakyReLU + segment max (encoded uint atomicMax)
__device__ __forceinline__ unsigned enc_f32(float f) {
    unsigned b = __float_as_uint(f);
    return (b & 0x80000000u) ? ~b : (b | 0x80000000u);
}
__device__ __forceinline__ float dec_f32(unsigned u) {
    unsigned b = (u & 0x80000000u) ? (u & 0x7FFFFFFFu) : ~u;
    return __uint_as_float(b);
}

__global__ void elogit_kernel(const float* __restrict__ e_w,
                              const int* __restrict__ src, const int* __restrict__ dst,
                              const float* __restrict__ el, const float* __restrict__ er,
                              const float* __restrict__ attn_ew,
                              float* __restrict__ e_buf, unsigned* __restrict__ emax) {
    const int tid = blockIdx.x * blockDim.x + threadIdx.x;
    if (tid >= N_EDGES * HEADS) return;
    const int h = tid & 3, e = tid >> 2;
    const int s = src[e], d = dst[e];
    float2 ew = *(const float2*)(e_w + (size_t)tid * 2);
    float2 aw = *(const float2*)(attn_ew + h * 2);
    float v = el[s * 4 + h] + er[d * 4 + h] + ew.x * aw.x + ew.y * aw.y;
    v = v > 0.f ? v : NEG_SLOPE * v;
    e_buf[tid] = v;
    atomicMax(emax + d * 4 + h, enc_f32(v));
}

// ---------------- exp(e - max) + segment sum
__global__ void eexp_kernel(const int* __restrict__ dst,
                            const unsigned* __restrict__ emax,
                            float* __restrict__ e_buf, float* __restrict__ denom) {
    const int tid = blockIdx.x * blockDim.x + threadIdx.x;
    if (tid >= N_EDGES * HEADS) return;
    const int h = tid & 3, e = tid >> 2;
    const int d = dst[e];
    const float m = dec_f32(emax[d * 4 + h]);
    const float ex = __expf(e_buf[tid] - m);
    e_buf[tid] = ex;
    atomicAdd(denom + d * 4 + h, ex);
}

// ---------------- weighted scatter-sum aggregation (atomic)
__global__ void agg_kernel(const int* __restrict__ src, const int* __restrict__ dst,
                           const float* __restrict__ fs, const float* __restrict__ e_buf,
                           const float* __restrict__ denom, float* __restrict__ out) {
    const int tid = blockIdx.x * blockDim.x + threadIdx.x;
    if (tid >= N_EDGES * HF) return;  // 204.8M < 2^31
    const int e = tid >> 7, idx = tid & 127, h = idx >> 5;
    const int s = src[e], d = dst[e];
    const float w = e_buf[e * 4 + h] / denom[d * 4 + h];
    atomicAdd(out + (size_t)d * HF + idx, fs[(size_t)s * HF + idx] * w);
}

// ---------------- ELU in-place
__global__ void elu_kernel(float* __restrict__ out) {
    const int tid = blockIdx.x * blockDim.x + threadIdx.x;
    if (tid >= N_NODES * HF) return;
    const float x = out[tid];
    out[tid] = x > 0.f ? x : expm1f(x);
}

extern "C" void kernel_launch(void* const* d_in, const int* in_sizes, int n_in,
                              void* d_out, int out_size, void* d_ws, size_t ws_size,
                              hipStream_t stream) {
    const float* feat    = (const float*)d_in[0];
    const float* e_w     = (const float*)d_in[1];
    const int*   src     = (const int*)d_in[2];
    const int*   dst     = (const int*)d_in[3];
    const float* W       = (const float*)d_in[4];
    const float* attn_l  = (const float*)d_in[5];
    const float* attn_r  = (const float*)d_in[6];
    const float* attn_ew = (const float*)d_in[7];
    float* out = (float*)d_out;

    char* ws = (char*)d_ws;
    float*    feat_src = (float*)ws;                       // N*128 f32 = 51.2 MB
    float*    el       = (float*)(ws + (size_t)N_NODES * HF * 4);
    float*    er       = el + N_NODES * HEADS;             // 1.6 MB each
    float*    e_buf    = er + N_NODES * HEADS;             // E*4 f32 = 25.6 MB
    unsigned* emax     = (unsigned*)(e_buf + (size_t)N_EDGES * HEADS);
    float*    denom    = (float*)(emax + N_NODES * HEADS);

    hipMemsetAsync(d_out, 0, (size_t)N_NODES * HF * sizeof(float), stream);
    hipMemsetAsync(emax, 0, (size_t)N_NODES * HEADS * 4, stream);
    hipMemsetAsync(denom, 0, (size_t)N_NODES * HEADS * 4, stream);

    gemm_kernel<<<(N_NODES + BN - 1) / BN, 256, 0, stream>>>(feat, W, feat_src);
    elr_kernel<<<(N_NODES * HEADS + 255) / 256, 256, 0, stream>>>(feat_src, attn_l, attn_r, el, er);
    elogit_kernel<<<(N_EDGES * HEADS + 255) / 256, 256, 0, stream>>>(e_w, src, dst, el, er, attn_ew, e_buf, emax);
    eexp_kernel<<<(N_EDGES * HEADS + 255) / 256, 256, 0, stream>>>(dst, emax, e_buf, denom);
    agg_kernel<<<(N_EDGES * HF + 255) / 256, 256, 0, stream>>>(src, dst, feat_src, e_buf, denom, out);
    elu_kernel<<<(N_NODES * HF + 255) / 256, 256, 0, stream>>>(out);
}

// Round 2
// 794.343 us; speedup vs baseline: 1.4010x; 1.4010x over previous
//
#include <hip/hip_runtime.h>

#define N_NODES 100000
#define N_EDGES 1600000
#define IN_F 256
#define OUT_F 32
#define HEADS 4
#define HF 128  // HEADS*OUT_F
#define NEG_SLOPE 0.2f

#define SCAN_B 512
#define NB1 ((N_NODES + SCAN_B - 1) / SCAN_B)  // 196

// ---------------- GEMM: feat_src = feat @ W^T  ([N,256] x [128,256]^T -> [N,128])
#define BN 64
#define BK 32

__global__ __launch_bounds__(256) void gemm_kernel(const float* __restrict__ feat,
                                                   const float* __restrict__ W,
                                                   float* __restrict__ feat_src) {
    __shared__ float fT[BN][36];
    __shared__ float wT[HF][36];
    const int t  = threadIdx.x;
    const int tx = t & 15;
    const int ty = t >> 4;
    const int n0 = blockIdx.x * BN;

    float acc[4][8];
#pragma unroll
    for (int i = 0; i < 4; ++i)
#pragma unroll
        for (int j = 0; j < 8; ++j) acc[i][j] = 0.f;

    for (int k0 = 0; k0 < IN_F; k0 += BK) {
        {
            const int nn = t >> 2, kk = (t & 3) * 8;
            const int n = n0 + nn;
            float4 a, b;
            if (n < N_NODES) {
                const float* p = feat + (size_t)n * IN_F + k0 + kk;
                a = *(const float4*)p;
                b = *(const float4*)(p + 4);
            } else {
                a = make_float4(0.f, 0.f, 0.f, 0.f);
                b = a;
            }
            float* q = &fT[nn][kk];
            *(float4*)q       = a;
            *(float4*)(q + 4) = b;
        }
        {
            const int o = t >> 1, kk = (t & 1) * 16;
            const float* p = W + (size_t)o * IN_F + k0 + kk;
            float4 a = *(const float4*)p;
            float4 b = *(const float4*)(p + 4);
            float4 c = *(const float4*)(p + 8);
            float4 d = *(const float4*)(p + 12);
            float* q = &wT[o][kk];
            ((float4*)q)[0] = a; ((float4*)q)[1] = b;
            ((float4*)q)[2] = c; ((float4*)q)[3] = d;
        }
        __syncthreads();

#pragma unroll
        for (int kk = 0; kk < BK; kk += 4) {
            float4 fv[4], wv[8];
#pragma unroll
            for (int i = 0; i < 4; ++i) fv[i] = *(const float4*)&fT[ty * 4 + i][kk];
#pragma unroll
            for (int j = 0; j < 8; ++j) wv[j] = *(const float4*)&wT[tx + 16 * j][kk];
#pragma unroll
            for (int i = 0; i < 4; ++i)
#pragma unroll
                for (int j = 0; j < 8; ++j) {
                    acc[i][j] += fv[i].x * wv[j].x + fv[i].y * wv[j].y +
                                 fv[i].z * wv[j].z + fv[i].w * wv[j].w;
                }
        }
        __syncthreads();
    }

#pragma unroll
    for (int i = 0; i < 4; ++i) {
        const int n = n0 + ty * 4 + i;
        if (n >= N_NODES) break;
#pragma unroll
        for (int j = 0; j < 8; ++j) feat_src[(size_t)n * HF + tx + 16 * j] = acc[i][j];
    }
}

// ---------------- per-node attention logits el/er
__global__ void elr_kernel(const float* __restrict__ fs,
                           const float* __restrict__ attn_l,
                           const float* __restrict__ attn_r,
                           float* __restrict__ el, float* __restrict__ er) {
    const int tid = blockIdx.x * blockDim.x + threadIdx.x;
    if (tid >= N_NODES * HEADS) return;
    const int h = tid & 3, n = tid >> 2;
    const float* p = fs + (size_t)n * HF + h * OUT_F;
    float sl = 0.f, sr = 0.f;
#pragma unroll
    for (int f = 0; f < OUT_F; f += 4) {
        float4 v  = *(const float4*)(p + f);
        float4 al = *(const float4*)(attn_l + h * OUT_F + f);
        float4 ar = *(const float4*)(attn_r + h * OUT_F + f);
        sl += v.x * al.x + v.y * al.y + v.z * al.z + v.w * al.w;
        sr += v.x * ar.x + v.y * ar.y + v.z * ar.z + v.w * ar.w;
    }
    el[tid] = sl;
    er[tid] = sr;
}

// ---------------- CSR build: histogram
__global__ void hist_kernel(const int* __restrict__ dst, int* __restrict__ cnt) {
    const int e = blockIdx.x * blockDim.x + threadIdx.x;
    if (e >= N_EDGES) return;
    atomicAdd(cnt + dst[e], 1);
}

// ---------------- CSR build: 3-step exclusive scan over 100K counts
__global__ __launch_bounds__(SCAN_B) void scan1_kernel(const int* __restrict__ cnt,
                                                       int* __restrict__ offs,
                                                       int* __restrict__ bsum) {
    __shared__ int sh[SCAN_B];
    const int t = threadIdx.x;
    const int i = blockIdx.x * SCAN_B + t;
    const int v = (i < N_NODES) ? cnt[i] : 0;
    sh[t] = v;
    __syncthreads();
    for (int off = 1; off < SCAN_B; off <<= 1) {
        const int x = (t >= off) ? sh[t - off] : 0;
        __syncthreads();
        sh[t] += x;
        __syncthreads();
    }
    if (i < N_NODES) offs[i] = sh[t] - v;  // exclusive
    if (t == SCAN_B - 1) bsum[blockIdx.x] = sh[t];
}

__global__ __launch_bounds__(256) void scan2_kernel(int* __restrict__ bsum) {
    __shared__ int sh[256];
    const int t = threadIdx.x;
    const int v = (t < NB1) ? bsum[t] : 0;
    sh[t] = v;
    __syncthreads();
    for (int off = 1; off < 256; off <<= 1) {
        const int x = (t >= off) ? sh[t - off] : 0;
        __syncthreads();
        sh[t] += x;
        __syncthreads();
    }
    if (t < NB1) bsum[t] = sh[t] - v;  // exclusive
}

__global__ __launch_bounds__(SCAN_B) void scan3_kernel(int* __restrict__ offs,
                                                       const int* __restrict__ bsum) {
    const int i = blockIdx.x * SCAN_B + threadIdx.x;
    if (i < N_NODES) offs[i] += bsum[blockIdx.x];
}

// ---------------- scatter: compute edge logits (4 heads) + place into CSR slots
__global__ void scatter_kernel(const float* __restrict__ e_w,
                               const int* __restrict__ src, const int* __restrict__ dst,
                               const float* __restrict__ el, const float* __restrict__ er,
                               const float* __restrict__ attn_ew,
                               const int* __restrict__ offs, int* __restrict__ cursor,
                               int* __restrict__ ssrc, float* __restrict__ slog) {
    const int e = blockIdx.x * blockDim.x + threadIdx.x;
    if (e >= N_EDGES) return;
    const int s = src[e], d = dst[e];
    const float4 l4 = *(const float4*)(el + (size_t)s * 4);
    const float4 r4 = *(const float4*)(er + (size_t)d * 4);
    const float4 w01 = *(const float4*)(e_w + (size_t)e * 8);
    const float4 w23 = *(const float4*)(e_w + (size_t)e * 8 + 4);
    const float4 a01 = *(const float4*)(attn_ew);
    const float4 a23 = *(const float4*)(attn_ew + 4);
    float v0 = l4.x + r4.x + w01.x * a01.x + w01.y * a01.y;
    float v1 = l4.y + r4.y + w01.z * a01.z + w01.w * a01.w;
    float v2 = l4.z + r4.z + w23.x * a23.x + w23.y * a23.y;
    float v3 = l4.w + r4.w + w23.z * a23.z + w23.w * a23.w;
    v0 = v0 > 0.f ? v0 : NEG_SLOPE * v0;
    v1 = v1 > 0.f ? v1 : NEG_SLOPE * v1;
    v2 = v2 > 0.f ? v2 : NEG_SLOPE * v2;
    v3 = v3 > 0.f ? v3 : NEG_SLOPE * v3;
    const int pos  = atomicAdd(cursor + d, 1);
    const int slot = offs[d] + pos;
    ssrc[slot] = s;
    *(float4*)(slog + (size_t)slot * 4) = make_float4(v0, v1, v2, v3);
}

// ---------------- aggregation: per dst node, fused softmax + gather-sum + ELU
__global__ __launch_bounds__(128) void agg_kernel(const int* __restrict__ offs,
                                                  const int* __restrict__ cnt,
                                                  const int* __restrict__ ssrc,
                                                  const float* __restrict__ slog,
                                                  const float* __restrict__ fs,
                                                  float* __restrict__ out) {
    const int n   = blockIdx.x;
    const int idx = threadIdx.x;   // 0..127: h = idx>>5, f = idx&31
    const int h   = idx >> 5;
    const int beg = offs[n];
    const int deg = cnt[n];

    float m = -1e30f;
    for (int j = 0; j < deg; ++j)
        m = fmaxf(m, slog[(size_t)(beg + j) * 4 + h]);

    float den = 0.f, acc = 0.f;
    for (int j = 0; j < deg; ++j) {
        const float w = __expf(slog[(size_t)(beg + j) * 4 + h] - m);
        den += w;
        const int s = ssrc[beg + j];
        acc += fs[(size_t)s * HF + idx] * w;
    }
    float r = (deg > 0) ? acc / den : 0.f;
    out[(size_t)n * HF + idx] = r > 0.f ? r : expm1f(r);
}

extern "C" void kernel_launch(void* const* d_in, const int* in_sizes, int n_in,
                              void* d_out, int out_size, void* d_ws, size_t ws_size,
                              hipStream_t stream) {
    const float* feat    = (const float*)d_in[0];
    const float* e_w     = (const float*)d_in[1];
    const int*   src     = (const int*)d_in[2];
    const int*   dst     = (const int*)d_in[3];
    const float* W       = (const float*)d_in[4];
    const float* attn_l  = (const float*)d_in[5];
    const float* attn_r  = (const float*)d_in[6];
    const float* attn_ew = (const float*)d_in[7];
    float* out = (float*)d_out;

    float* feat_src = (float*)d_ws;                        // 51.2 MB
    float* el       = feat_src + (size_t)N_NODES * HF;     // 1.6 MB
    float* er       = el + (size_t)N_NODES * HEADS;        // 1.6 MB
    int*   counts   = (int*)(er + (size_t)N_NODES * HEADS);// 0.4 MB
    int*   offs     = counts + N_NODES;                    // 0.4 MB
    int*   cursor   = offs + N_NODES;                      // 0.4 MB
    int*   bsum     = cursor + N_NODES;                    // 4 KB
    int*   ssrc     = bsum + 1024;                         // 6.4 MB
    float* slog     = (float*)(ssrc + N_EDGES);            // 25.6 MB

    hipMemsetAsync(counts, 0, N_NODES * sizeof(int), stream);
    hipMemsetAsync(cursor, 0, N_NODES * sizeof(int), stream);

    gemm_kernel<<<(N_NODES + BN - 1) / BN, 256, 0, stream>>>(feat, W, feat_src);
    elr_kernel<<<(N_NODES * HEADS + 255) / 256, 256, 0, stream>>>(feat_src, attn_l, attn_r, el, er);
    hist_kernel<<<(N_EDGES + 255) / 256, 256, 0, stream>>>(dst, counts);
    scan1_kernel<<<NB1, SCAN_B, 0, stream>>>(counts, offs, bsum);
    scan2_kernel<<<1, 256, 0, stream>>>(bsum);
    scan3_kernel<<<NB1, SCAN_B, 0, stream>>>(offs, bsum);
    scatter_kernel<<<(N_EDGES + 255) / 256, 256, 0, stream>>>(e_w, src, dst, el, er, attn_ew,
                                                              offs, cursor, ssrc, slog);
    agg_kernel<<<N_NODES, 128, 0, stream>>>(offs, counts, ssrc, slog, feat_src, out);
}

// Round 3
// 423.861 us; speedup vs baseline: 2.6256x; 1.8741x over previous
//
#include <hip/hip_runtime.h>

#define N_NODES 100000
#define N_EDGES 1600000
#define IN_F 256
#define OUT_F 32
#define HEADS 4
#define HF 128  // HEADS*OUT_F
#define NEG_SLOPE 0.2f

#define SCAN_B 512
#define NB1 ((N_NODES + SCAN_B - 1) / SCAN_B)  // 196

typedef __attribute__((ext_vector_type(8))) short bf16x8;
typedef __attribute__((ext_vector_type(4))) float f32x4;

__device__ __forceinline__ ushort f2b(float x) {
    unsigned u = __float_as_uint(x);
    unsigned r = (u + 0x7FFFu + ((u >> 16) & 1u)) >> 16;   // round-to-nearest-even
    return (ushort)r;
}
__device__ __forceinline__ float b2f(ushort h) {
    return __uint_as_float(((unsigned)h) << 16);
}

// ---------------- MFMA GEMM: fsb = bf16( f32(feat) @ W^T )  [N,256]x[128,256]^T -> [N,128]
// block: 256 thr = 4 waves; tile M=64 (16 rows/wave), N=128 (8 mfma tiles), K staged 64
__global__ __launch_bounds__(256) void gemm_mfma(const float* __restrict__ feat,
                                                 const float* __restrict__ W,
                                                 ushort* __restrict__ fsb) {
    __shared__ ushort shA[64 * 64];    // 8 KB, row = 128B, XOR-swizzled
    __shared__ ushort shB[128 * 64];   // 16 KB
    const int t = threadIdx.x;
    const int w = t >> 6, l = t & 63;
    const int lr = l & 15, lk = l >> 4;
    const int n0 = blockIdx.x * 64;

    f32x4 acc[8];
#pragma unroll
    for (int i = 0; i < 8; ++i) acc[i] = (f32x4){0.f, 0.f, 0.f, 0.f};

    for (int k0 = 0; k0 < IN_F; k0 += 64) {
        // stage A: 64 nodes x 64 k (f32 -> bf16), thread t: row t>>2, 4 float4
        {
            const int r = t >> 2;
            const int n = n0 + r;
            const float* p = feat + (size_t)n * IN_F + k0 + (t & 3) * 16;
#pragma unroll
            for (int i = 0; i < 4; ++i) {
                const int c4 = (t & 3) * 4 + i;           // float4 index 0..15
                float4 v = make_float4(0.f, 0.f, 0.f, 0.f);
                if (n < N_NODES) v = *(const float4*)(p + i * 4);
                ushort4 hv = { f2b(v.x), f2b(v.y), f2b(v.z), f2b(v.w) };
                const int addr = r * 128 + ((c4 * 8) ^ ((r & 7) << 4));
                *(ushort4*)((char*)shA + addr) = hv;
            }
        }
        // stage B: 128 rows x 64 k, thread t: row t>>1, 8 float4
        {
            const int r = t >> 1;
            const float* p = W + (size_t)r * IN_F + k0 + (t & 1) * 32;
#pragma unroll
            for (int i = 0; i < 8; ++i) {
                const int c4 = (t & 1) * 8 + i;
                float4 v = *(const float4*)(p + i * 4);
                ushort4 hv = { f2b(v.x), f2b(v.y), f2b(v.z), f2b(v.w) };
                const int addr = r * 128 + ((c4 * 8) ^ ((r & 7) << 4));
                *(ushort4*)((char*)shB + addr) = hv;
            }
        }
        __syncthreads();
#pragma unroll
        for (int ks = 0; ks < 2; ++ks) {
            const int ra = w * 16 + lr;
            bf16x8 a = *(bf16x8*)((char*)shA + ra * 128 + ((ks * 64 + lk * 16) ^ ((ra & 7) << 4)));
#pragma unroll
            for (int ot = 0; ot < 8; ++ot) {
                const int rb = ot * 16 + lr;
                bf16x8 b = *(bf16x8*)((char*)shB + rb * 128 + ((ks * 64 + lk * 16) ^ ((rb & 7) << 4)));
                acc[ot] = __builtin_amdgcn_mfma_f32_16x16x32_bf16(a, b, acc[ot], 0, 0, 0);
            }
        }
        __syncthreads();
    }
    // D: col = lane&15, row = (lane>>4)*4 + reg  [guide §3, m89-verified]
#pragma unroll
    for (int reg = 0; reg < 4; ++reg) {
        const int n = n0 + w * 16 + lk * 4 + reg;
        if (n < N_NODES) {
#pragma unroll
            for (int ot = 0; ot < 8; ++ot)
                fsb[(size_t)n * HF + ot * 16 + lr] = f2b(acc[ot][reg]);
        }
    }
}

// ---------------- per-node attention logits el/er (bf16 feat_src)
__global__ void elr_kernel(const ushort* __restrict__ fsb,
                           const float* __restrict__ attn_l,
                           const float* __restrict__ attn_r,
                           float* __restrict__ el, float* __restrict__ er) {
    const int tid = blockIdx.x * blockDim.x + threadIdx.x;
    if (tid >= N_NODES * HEADS) return;
    const int h = tid & 3, n = tid >> 2;
    const ushort* p = fsb + (size_t)n * HF + h * OUT_F;
    float sl = 0.f, sr = 0.f;
#pragma unroll
    for (int f = 0; f < OUT_F; f += 8) {
        ushort4 a = *(const ushort4*)(p + f);
        ushort4 b = *(const ushort4*)(p + f + 4);
        float v[8] = { b2f(a.x), b2f(a.y), b2f(a.z), b2f(a.w),
                       b2f(b.x), b2f(b.y), b2f(b.z), b2f(b.w) };
#pragma unroll
        for (int j = 0; j < 8; ++j) {
            sl += v[j] * attn_l[h * OUT_F + f + j];
            sr += v[j] * attn_r[h * OUT_F + f + j];
        }
    }
    el[tid] = sl;
    er[tid] = sr;
}

// ---------------- CSR build: histogram
__global__ void hist_kernel(const int* __restrict__ dst, int* __restrict__ cnt) {
    const int e = blockIdx.x * blockDim.x + threadIdx.x;
    if (e >= N_EDGES) return;
    atomicAdd(cnt + dst[e], 1);
}

// ---------------- CSR build: 3-step exclusive scan
__global__ __launch_bounds__(SCAN_B) void scan1_kernel(const int* __restrict__ cnt,
                                                       int* __restrict__ offs,
                                                       int* __restrict__ bsum) {
    __shared__ int sh[SCAN_B];
    const int t = threadIdx.x;
    const int i = blockIdx.x * SCAN_B + t;
    const int v = (i < N_NODES) ? cnt[i] : 0;
    sh[t] = v;
    __syncthreads();
    for (int off = 1; off < SCAN_B; off <<= 1) {
        const int x = (t >= off) ? sh[t - off] : 0;
        __syncthreads();
        sh[t] += x;
        __syncthreads();
    }
    if (i < N_NODES) offs[i] = sh[t] - v;
    if (t == SCAN_B - 1) bsum[blockIdx.x] = sh[t];
}

__global__ __launch_bounds__(256) void scan2_kernel(int* __restrict__ bsum) {
    __shared__ int sh[256];
    const int t = threadIdx.x;
    const int v = (t < NB1) ? bsum[t] : 0;
    sh[t] = v;
    __syncthreads();
    for (int off = 1; off < 256; off <<= 1) {
        const int x = (t >= off) ? sh[t - off] : 0;
        __syncthreads();
        sh[t] += x;
        __syncthreads();
    }
    if (t < NB1) bsum[t] = sh[t] - v;
}

__global__ __launch_bounds__(SCAN_B) void scan3_kernel(int* __restrict__ offs,
                                                       const int* __restrict__ bsum) {
    const int i = blockIdx.x * SCAN_B + threadIdx.x;
    if (i < N_NODES) offs[i] += bsum[blockIdx.x];
}

// ---------------- scatter: edge logits (4 heads) -> CSR slots
__global__ void scatter_kernel(const float* __restrict__ e_w,
                               const int* __restrict__ src, const int* __restrict__ dst,
                               const float* __restrict__ el, const float* __restrict__ er,
                               const float* __restrict__ attn_ew,
                               const int* __restrict__ offs, int* __restrict__ cursor,
                               int* __restrict__ ssrc, float* __restrict__ slog) {
    const int e = blockIdx.x * blockDim.x + threadIdx.x;
    if (e >= N_EDGES) return;
    const int s = src[e], d = dst[e];
    const float4 l4 = *(const float4*)(el + (size_t)s * 4);
    const float4 r4 = *(const float4*)(er + (size_t)d * 4);
    const float4 w01 = *(const float4*)(e_w + (size_t)e * 8);
    const float4 w23 = *(const float4*)(e_w + (size_t)e * 8 + 4);
    const float4 a01 = *(const float4*)(attn_ew);
    const float4 a23 = *(const float4*)(attn_ew + 4);
    float v0 = l4.x + r4.x + w01.x * a01.x + w01.y * a01.y;
    float v1 = l4.y + r4.y + w01.z * a01.z + w01.w * a01.w;
    float v2 = l4.z + r4.z + w23.x * a23.x + w23.y * a23.y;
    float v3 = l4.w + r4.w + w23.z * a23.z + w23.w * a23.w;
    v0 = v0 > 0.f ? v0 : NEG_SLOPE * v0;
    v1 = v1 > 0.f ? v1 : NEG_SLOPE * v1;
    v2 = v2 > 0.f ? v2 : NEG_SLOPE * v2;
    v3 = v3 > 0.f ? v3 : NEG_SLOPE * v3;
    const int pos  = atomicAdd(cursor + d, 1);
    const int slot = offs[d] + pos;
    ssrc[slot] = s;
    *(float4*)(slog + (size_t)slot * 4) = make_float4(v0, v1, v2, v3);
}

// ---------------- aggregation: per-node LDS-staged softmax + bf16 gather-sum + ELU
#define CH 64
__global__ __launch_bounds__(128) void agg_kernel(const int* __restrict__ offs,
                                                  const int* __restrict__ cnt,
                                                  const int* __restrict__ ssrc,
                                                  const float* __restrict__ slog,
                                                  const ushort* __restrict__ fsb,
                                                  float* __restrict__ out) {
    __shared__ float sh_log[CH * 4];
    __shared__ int   sh_src[CH];
    const int n   = blockIdx.x;
    const int idx = threadIdx.x;   // 0..127
    const int h   = idx >> 5;
    const int beg = offs[n];
    const int deg = cnt[n];

    float m = -1e30f, den = 0.f, acc = 0.f;
    for (int c = 0; c < deg; c += CH) {
        const int cn = min(CH, deg - c);
        if (idx < CH) {
            if (idx < cn)
                *(float4*)&sh_log[idx * 4] = *(const float4*)(slog + (size_t)(beg + c + idx) * 4);
        } else {
            const int j = idx - CH;
            if (j < cn) sh_src[j] = ssrc[beg + c + j];
        }
        __syncthreads();
        float cm = m;
        for (int j = 0; j < cn; ++j) cm = fmaxf(cm, sh_log[j * 4 + h]);
        const float scale = __expf(m - cm);   // first chunk: exp(-huge) = 0, acc/den already 0
        acc *= scale; den *= scale; m = cm;
        for (int j = 0; j < cn; ++j) {
            const float wgt = __expf(sh_log[j * 4 + h] - m);
            const int s = sh_src[j];
            acc += wgt * b2f(fsb[(size_t)s * HF + idx]);
            den += wgt;
        }
        __syncthreads();
    }
    const float r = (deg > 0) ? acc / den : 0.f;
    out[(size_t)n * HF + idx] = r > 0.f ? r : expm1f(r);
}

extern "C" void kernel_launch(void* const* d_in, const int* in_sizes, int n_in,
                              void* d_out, int out_size, void* d_ws, size_t ws_size,
                              hipStream_t stream) {
    const float* feat    = (const float*)d_in[0];
    const float* e_w     = (const float*)d_in[1];
    const int*   src     = (const int*)d_in[2];
    const int*   dst     = (const int*)d_in[3];
    const float* W       = (const float*)d_in[4];
    const float* attn_l  = (const float*)d_in[5];
    const float* attn_r  = (const float*)d_in[6];
    const float* attn_ew = (const float*)d_in[7];
    float* out = (float*)d_out;

    ushort* fsb    = (ushort*)d_ws;                          // 25.6 MB bf16 feat_src
    float*  el     = (float*)(fsb + (size_t)N_NODES * HF);
    float*  er     = el + (size_t)N_NODES * HEADS;
    int*    counts = (int*)(er + (size_t)N_NODES * HEADS);
    int*    offs   = counts + N_NODES;
    int*    cursor = offs + N_NODES;
    int*    bsum   = cursor + N_NODES;
    int*    ssrc   = bsum + 1024;                            // 6.4 MB
    float*  slog   = (float*)(ssrc + N_EDGES);               // 25.6 MB

    hipMemsetAsync(counts, 0, N_NODES * sizeof(int), stream);
    hipMemsetAsync(cursor, 0, N_NODES * sizeof(int), stream);

    gemm_mfma<<<(N_NODES + 63) / 64, 256, 0, stream>>>(feat, W, fsb);
    elr_kernel<<<(N_NODES * HEADS + 255) / 256, 256, 0, stream>>>(fsb, attn_l, attn_r, el, er);
    hist_kernel<<<(N_EDGES + 255) / 256, 256, 0, stream>>>(dst, counts);
    scan1_kernel<<<NB1, SCAN_B, 0, stream>>>(counts, offs, bsum);
    scan2_kernel<<<1, 256, 0, stream>>>(bsum);
    scan3_kernel<<<NB1, SCAN_B, 0, stream>>>(offs, bsum);
    scatter_kernel<<<(N_EDGES + 255) / 256, 256, 0, stream>>>(e_w, src, dst, el, er, attn_ew,
                                                              offs, cursor, ssrc, slog);
    agg_kernel<<<N_NODES, 128, 0, stream>>>(offs, counts, ssrc, slog, fsb, out);
}

// Round 4
// 372.187 us; speedup vs baseline: 2.9902x; 1.1388x over previous
//
#include <hip/hip_runtime.h>
#include <hip/hip_fp16.h>

#define N_NODES 100000
#define N_EDGES 1600000
#define IN_F 256
#define OUT_F 32
#define HEADS 4
#define HF 128  // HEADS*OUT_F
#define NEG_SLOPE 0.2f

#define SCAN_B 512
#define NB1 ((N_NODES + SCAN_B - 1) / SCAN_B)  // 196

typedef __attribute__((ext_vector_type(8))) short bf16x8;
typedef __attribute__((ext_vector_type(4))) float f32x4;

__device__ __forceinline__ ushort f2b(float x) {
    unsigned u = __float_as_uint(x);
    unsigned r = (u + 0x7FFFu + ((u >> 16) & 1u)) >> 16;   // round-to-nearest-even
    return (ushort)r;
}
__device__ __forceinline__ float b2f(ushort h) {
    return __uint_as_float(((unsigned)h) << 16);
}
__device__ __forceinline__ unsigned pack_h2(float a, float b) {
    return (unsigned)__half_as_ushort(__float2half_rn(a)) |
           ((unsigned)__half_as_ushort(__float2half_rn(b)) << 16);
}
__device__ __forceinline__ float unpack_lo(unsigned u) {
    return __half2float(__ushort_as_half((ushort)(u & 0xFFFFu)));
}
__device__ __forceinline__ float unpack_hi(unsigned u) {
    return __half2float(__ushort_as_half((ushort)(u >> 16)));
}

// ---------------- MFMA GEMM: fsb = bf16( f32(feat) @ W^T )  [N,256]x[128,256]^T -> [N,128]
__global__ __launch_bounds__(256) void gemm_mfma(const float* __restrict__ feat,
                                                 const float* __restrict__ W,
                                                 ushort* __restrict__ fsb) {
    __shared__ ushort shA[64 * 64];    // 8 KB, row = 128B, XOR-swizzled
    __shared__ ushort shB[128 * 64];   // 16 KB
    const int t = threadIdx.x;
    const int w = t >> 6, l = t & 63;
    const int lr = l & 15, lk = l >> 4;
    const int n0 = blockIdx.x * 64;

    f32x4 acc[8];
#pragma unroll
    for (int i = 0; i < 8; ++i) acc[i] = (f32x4){0.f, 0.f, 0.f, 0.f};

    for (int k0 = 0; k0 < IN_F; k0 += 64) {
        {
            const int r = t >> 2;
            const int n = n0 + r;
            const float* p = feat + (size_t)n * IN_F + k0 + (t & 3) * 16;
#pragma unroll
            for (int i = 0; i < 4; ++i) {
                const int c4 = (t & 3) * 4 + i;
                float4 v = make_float4(0.f, 0.f, 0.f, 0.f);
                if (n < N_NODES) v = *(const float4*)(p + i * 4);
                ushort4 hv = { f2b(v.x), f2b(v.y), f2b(v.z), f2b(v.w) };
                const int addr = r * 128 + ((c4 * 8) ^ ((r & 7) << 4));
                *(ushort4*)((char*)shA + addr) = hv;
            }
        }
        {
            const int r = t >> 1;
            const float* p = W + (size_t)r * IN_F + k0 + (t & 1) * 32;
#pragma unroll
            for (int i = 0; i < 8; ++i) {
                const int c4 = (t & 1) * 8 + i;
                float4 v = *(const float4*)(p + i * 4);
                ushort4 hv = { f2b(v.x), f2b(v.y), f2b(v.z), f2b(v.w) };
                const int addr = r * 128 + ((c4 * 8) ^ ((r & 7) << 4));
                *(ushort4*)((char*)shB + addr) = hv;
            }
        }
        __syncthreads();
#pragma unroll
        for (int ks = 0; ks < 2; ++ks) {
            const int ra = w * 16 + lr;
            bf16x8 a = *(bf16x8*)((char*)shA + ra * 128 + ((ks * 64 + lk * 16) ^ ((ra & 7) << 4)));
#pragma unroll
            for (int ot = 0; ot < 8; ++ot) {
                const int rb = ot * 16 + lr;
                bf16x8 b = *(bf16x8*)((char*)shB + rb * 128 + ((ks * 64 + lk * 16) ^ ((rb & 7) << 4)));
                acc[ot] = __builtin_amdgcn_mfma_f32_16x16x32_bf16(a, b, acc[ot], 0, 0, 0);
            }
        }
        __syncthreads();
    }
#pragma unroll
    for (int reg = 0; reg < 4; ++reg) {
        const int n = n0 + w * 16 + lk * 4 + reg;
        if (n < N_NODES) {
#pragma unroll
            for (int ot = 0; ot < 8; ++ot)
                fsb[(size_t)n * HF + ot * 16 + lr] = f2b(acc[ot][reg]);
        }
    }
}

// ---------------- per-node attention logits el/er (bf16 feat_src)
__global__ void elr_kernel(const ushort* __restrict__ fsb,
                           const float* __restrict__ attn_l,
                           const float* __restrict__ attn_r,
                           float* __restrict__ el, float* __restrict__ er) {
    const int tid = blockIdx.x * blockDim.x + threadIdx.x;
    if (tid >= N_NODES * HEADS) return;
    const int h = tid & 3, n = tid >> 2;
    const ushort* p = fsb + (size_t)n * HF + h * OUT_F;
    float sl = 0.f, sr = 0.f;
#pragma unroll
    for (int f = 0; f < OUT_F; f += 8) {
        ushort4 a = *(const ushort4*)(p + f);
        ushort4 b = *(const ushort4*)(p + f + 4);
        float v[8] = { b2f(a.x), b2f(a.y), b2f(a.z), b2f(a.w),
                       b2f(b.x), b2f(b.y), b2f(b.z), b2f(b.w) };
#pragma unroll
        for (int j = 0; j < 8; ++j) {
            sl += v[j] * attn_l[h * OUT_F + f + j];
            sr += v[j] * attn_r[h * OUT_F + f + j];
        }
    }
    el[tid] = sl;
    er[tid] = sr;
}

// ---------------- CSR build: histogram
__global__ void hist_kernel(const int* __restrict__ dst, int* __restrict__ cnt) {
    const int e = blockIdx.x * blockDim.x + threadIdx.x;
    if (e >= N_EDGES) return;
    atomicAdd(cnt + dst[e], 1);
}

// ---------------- CSR build: 3-step exclusive scan
__global__ __launch_bounds__(SCAN_B) void scan1_kernel(const int* __restrict__ cnt,
                                                       int* __restrict__ offs,
                                                       int* __restrict__ bsum) {
    __shared__ int sh[SCAN_B];
    const int t = threadIdx.x;
    const int i = blockIdx.x * SCAN_B + t;
    const int v = (i < N_NODES) ? cnt[i] : 0;
    sh[t] = v;
    __syncthreads();
    for (int off = 1; off < SCAN_B; off <<= 1) {
        const int x = (t >= off) ? sh[t - off] : 0;
        __syncthreads();
        sh[t] += x;
        __syncthreads();
    }
    if (i < N_NODES) offs[i] = sh[t] - v;
    if (t == SCAN_B - 1) bsum[blockIdx.x] = sh[t];
}

__global__ __launch_bounds__(256) void scan2_kernel(int* __restrict__ bsum) {
    __shared__ int sh[256];
    const int t = threadIdx.x;
    const int v = (t < NB1) ? bsum[t] : 0;
    sh[t] = v;
    __syncthreads();
    for (int off = 1; off < 256; off <<= 1) {
        const int x = (t >= off) ? sh[t - off] : 0;
        __syncthreads();
        sh[t] += x;
        __syncthreads();
    }
    if (t < NB1) bsum[t] = sh[t] - v;
}

__global__ __launch_bounds__(SCAN_B) void scan3_kernel(int* __restrict__ offs,
                                                       const int* __restrict__ bsum) {
    const int i = blockIdx.x * SCAN_B + threadIdx.x;
    if (i < N_NODES) offs[i] += bsum[blockIdx.x];
}

// ---------------- scatter: one 16B record {src, 4 x f16 ewdot} per edge
__global__ void scatter_kernel(const float* __restrict__ e_w,
                               const int* __restrict__ src, const int* __restrict__ dst,
                               const float* __restrict__ attn_ew,
                               const int* __restrict__ offs, int* __restrict__ cursor,
                               int4* __restrict__ recs) {
    const int e = blockIdx.x * blockDim.x + threadIdx.x;
    if (e >= N_EDGES) return;
    const int s = src[e], d = dst[e];
    const float4 w01 = *(const float4*)(e_w + (size_t)e * 8);
    const float4 w23 = *(const float4*)(e_w + (size_t)e * 8 + 4);
    const float4 a01 = *(const float4*)(attn_ew);
    const float4 a23 = *(const float4*)(attn_ew + 4);
    const float d0 = w01.x * a01.x + w01.y * a01.y;
    const float d1 = w01.z * a01.z + w01.w * a01.w;
    const float d2 = w23.x * a23.x + w23.y * a23.y;
    const float d3 = w23.z * a23.z + w23.w * a23.w;
    const int pos  = atomicAdd(cursor + d, 1);
    const int slot = offs[d] + pos;
    int4 r;
    r.x = s;
    r.y = (int)pack_h2(d0, d1);
    r.z = (int)pack_h2(d2, d3);
    r.w = 0;
    recs[slot] = r;
}

// ---------------- aggregation: logits assembled in LDS + online softmax + bf16 gather + ELU
#define CH 64
__global__ __launch_bounds__(128) void agg_kernel(const int* __restrict__ offs,
                                                  const int* __restrict__ cnt,
                                                  const int4* __restrict__ recs,
                                                  const float* __restrict__ el,
                                                  const float* __restrict__ er,
                                                  const ushort* __restrict__ fsb,
                                                  float* __restrict__ out) {
    __shared__ float sh_log[CH * 4];
    __shared__ int   sh_src[CH];
    const int n   = blockIdx.x;
    const int idx = threadIdx.x;   // 0..127
    const int h   = idx >> 5;
    const int beg = offs[n];
    const int deg = cnt[n];
    const float4 ern = *(const float4*)(er + (size_t)n * 4);

    float m = -1e30f, den = 0.f, acc = 0.f;
    for (int c = 0; c < deg; c += CH) {
        const int cn = min(CH, deg - c);
        if (idx < cn) {
            const int4 r = recs[beg + c + idx];
            const int s = r.x;
            const float4 l4 = *(const float4*)(el + (size_t)s * 4);
            float v0 = l4.x + ern.x + unpack_lo((unsigned)r.y);
            float v1 = l4.y + ern.y + unpack_hi((unsigned)r.y);
            float v2 = l4.z + ern.z + unpack_lo((unsigned)r.z);
            float v3 = l4.w + ern.w + unpack_hi((unsigned)r.z);
            v0 = v0 > 0.f ? v0 : NEG_SLOPE * v0;
            v1 = v1 > 0.f ? v1 : NEG_SLOPE * v1;
            v2 = v2 > 0.f ? v2 : NEG_SLOPE * v2;
            v3 = v3 > 0.f ? v3 : NEG_SLOPE * v3;
            *(float4*)&sh_log[idx * 4] = make_float4(v0, v1, v2, v3);
            sh_src[idx] = s;
        }
        __syncthreads();
        float cm = m;
        for (int j = 0; j < cn; ++j) cm = fmaxf(cm, sh_log[j * 4 + h]);
        const float scale = __expf(m - cm);   // first chunk: exp(-huge)=0, acc/den already 0
        acc *= scale; den *= scale; m = cm;
#pragma unroll 4
        for (int j = 0; j < cn; ++j) {
            const float wgt = __expf(sh_log[j * 4 + h] - m);
            const int s = sh_src[j];
            acc += wgt * b2f(fsb[(size_t)s * HF + idx]);
            den += wgt;
        }
        __syncthreads();
    }
    const float r = (deg > 0) ? acc / den : 0.f;
    out[(size_t)n * HF + idx] = r > 0.f ? r : expm1f(r);
}

extern "C" void kernel_launch(void* const* d_in, const int* in_sizes, int n_in,
                              void* d_out, int out_size, void* d_ws, size_t ws_size,
                              hipStream_t stream) {
    const float* feat    = (const float*)d_in[0];
    const float* e_w     = (const float*)d_in[1];
    const int*   src     = (const int*)d_in[2];
    const int*   dst     = (const int*)d_in[3];
    const float* W       = (const float*)d_in[4];
    const float* attn_l  = (const float*)d_in[5];
    const float* attn_r  = (const float*)d_in[6];
    const float* attn_ew = (const float*)d_in[7];
    float* out = (float*)d_out;

    ushort* fsb    = (ushort*)d_ws;                          // 25.6 MB bf16 feat_src
    float*  el     = (float*)(fsb + (size_t)N_NODES * HF);   // 1.6 MB
    float*  er     = el + (size_t)N_NODES * HEADS;           // 1.6 MB
    int*    counts = (int*)(er + (size_t)N_NODES * HEADS);   // 0.4 MB
    int*    offs   = counts + N_NODES;                       // 0.4 MB
    int*    cursor = offs + N_NODES;                         // 0.4 MB
    int*    bsum   = cursor + N_NODES;                       // 4 KB
    int4*   recs   = (int4*)(bsum + 1024);                   // 25.6 MB

    hipMemsetAsync(counts, 0, N_NODES * sizeof(int), stream);
    hipMemsetAsync(cursor, 0, N_NODES * sizeof(int), stream);

    gemm_mfma<<<(N_NODES + 63) / 64, 256, 0, stream>>>(feat, W, fsb);
    elr_kernel<<<(N_NODES * HEADS + 255) / 256, 256, 0, stream>>>(fsb, attn_l, attn_r, el, er);
    hist_kernel<<<(N_EDGES + 255) / 256, 256, 0, stream>>>(dst, counts);
    scan1_kernel<<<NB1, SCAN_B, 0, stream>>>(counts, offs, bsum);
    scan2_kernel<<<1, 256, 0, stream>>>(bsum);
    scan3_kernel<<<NB1, SCAN_B, 0, stream>>>(offs, bsum);
    scatter_kernel<<<(N_EDGES + 255) / 256, 256, 0, stream>>>(e_w, src, dst, attn_ew,
                                                              offs, cursor, recs);
    agg_kernel<<<N_NODES, 128, 0, stream>>>(offs, counts, recs, el, er, fsb, out);
}

// Round 5
// 318.460 us; speedup vs baseline: 3.4946x; 1.1687x over previous
//
#include <hip/hip_runtime.h>
#include <hip/hip_fp16.h>

#define N_NODES 100000
#define N_EDGES 1600000
#define IN_F 256
#define OUT_F 32
#define HEADS 4
#define HF 128  // HEADS*OUT_F
#define NEG_SLOPE 0.2f

#define SCAN_B 512
#define NB1 ((N_NODES + SCAN_B - 1) / SCAN_B)  // 196

typedef __attribute__((ext_vector_type(8))) short bf16x8;
typedef __attribute__((ext_vector_type(4))) float f32x4;

__device__ __forceinline__ ushort f2b(float x) {
    unsigned u = __float_as_uint(x);
    unsigned r = (u + 0x7FFFu + ((u >> 16) & 1u)) >> 16;   // round-to-nearest-even
    return (ushort)r;
}
__device__ __forceinline__ float b2f(ushort h) {
    return __uint_as_float(((unsigned)h) << 16);
}
__device__ __forceinline__ unsigned pack_h2(float a, float b) {
    return (unsigned)__half_as_ushort(__float2half_rn(a)) |
           ((unsigned)__half_as_ushort(__float2half_rn(b)) << 16);
}
__device__ __forceinline__ float unpack_lo(unsigned u) {
    return __half2float(__ushort_as_half((ushort)(u & 0xFFFFu)));
}
__device__ __forceinline__ float unpack_hi(unsigned u) {
    return __half2float(__ushort_as_half((ushort)(u >> 16)));
}

// ---------------- MFMA GEMM: fsb = bf16( f32(feat) @ W^T )  [N,256]x[128,256]^T -> [N,128]
__global__ __launch_bounds__(256) void gemm_mfma(const float* __restrict__ feat,
                                                 const float* __restrict__ W,
                                                 ushort* __restrict__ fsb) {
    __shared__ ushort shA[64 * 64];    // 8 KB, row = 128B, XOR-swizzled
    __shared__ ushort shB[128 * 64];   // 16 KB
    const int t = threadIdx.x;
    const int w = t >> 6, l = t & 63;
    const int lr = l & 15, lk = l >> 4;
    const int n0 = blockIdx.x * 64;

    f32x4 acc[8];
#pragma unroll
    for (int i = 0; i < 8; ++i) acc[i] = (f32x4){0.f, 0.f, 0.f, 0.f};

    for (int k0 = 0; k0 < IN_F; k0 += 64) {
        {
            const int r = t >> 2;
            const int n = n0 + r;
            const float* p = feat + (size_t)n * IN_F + k0 + (t & 3) * 16;
#pragma unroll
            for (int i = 0; i < 4; ++i) {
                const int c4 = (t & 3) * 4 + i;
                float4 v = make_float4(0.f, 0.f, 0.f, 0.f);
                if (n < N_NODES) v = *(const float4*)(p + i * 4);
                ushort4 hv = { f2b(v.x), f2b(v.y), f2b(v.z), f2b(v.w) };
                const int addr = r * 128 + ((c4 * 8) ^ ((r & 7) << 4));
                *(ushort4*)((char*)shA + addr) = hv;
            }
        }
        {
            const int r = t >> 1;
            const float* p = W + (size_t)r * IN_F + k0 + (t & 1) * 32;
#pragma unroll
            for (int i = 0; i < 8; ++i) {
                const int c4 = (t & 1) * 8 + i;
                float4 v = *(const float4*)(p + i * 4);
                ushort4 hv = { f2b(v.x), f2b(v.y), f2b(v.z), f2b(v.w) };
                const int addr = r * 128 + ((c4 * 8) ^ ((r & 7) << 4));
                *(ushort4*)((char*)shB + addr) = hv;
            }
        }
        __syncthreads();
#pragma unroll
        for (int ks = 0; ks < 2; ++ks) {
            const int ra = w * 16 + lr;
            bf16x8 a = *(bf16x8*)((char*)shA + ra * 128 + ((ks * 64 + lk * 16) ^ ((ra & 7) << 4)));
#pragma unroll
            for (int ot = 0; ot < 8; ++ot) {
                const int rb = ot * 16 + lr;
                bf16x8 b = *(bf16x8*)((char*)shB + rb * 128 + ((ks * 64 + lk * 16) ^ ((rb & 7) << 4)));
                acc[ot] = __builtin_amdgcn_mfma_f32_16x16x32_bf16(a, b, acc[ot], 0, 0, 0);
            }
        }
        __syncthreads();
    }
#pragma unroll
    for (int reg = 0; reg < 4; ++reg) {
        const int n = n0 + w * 16 + lk * 4 + reg;
        if (n < N_NODES) {
#pragma unroll
            for (int ot = 0; ot < 8; ++ot)
                fsb[(size_t)n * HF + ot * 16 + lr] = f2b(acc[ot][reg]);
        }
    }
}

// ---------------- per-node attention logits el/er (bf16 feat_src)
__global__ void elr_kernel(const ushort* __restrict__ fsb,
                           const float* __restrict__ attn_l,
                           const float* __restrict__ attn_r,
                           float* __restrict__ el, float* __restrict__ er) {
    const int tid = blockIdx.x * blockDim.x + threadIdx.x;
    if (tid >= N_NODES * HEADS) return;
    const int h = tid & 3, n = tid >> 2;
    const ushort* p = fsb + (size_t)n * HF + h * OUT_F;
    float sl = 0.f, sr = 0.f;
#pragma unroll
    for (int f = 0; f < OUT_F; f += 8) {
        ushort4 a = *(const ushort4*)(p + f);
        ushort4 b = *(const ushort4*)(p + f + 4);
        float v[8] = { b2f(a.x), b2f(a.y), b2f(a.z), b2f(a.w),
                       b2f(b.x), b2f(b.y), b2f(b.z), b2f(b.w) };
#pragma unroll
        for (int j = 0; j < 8; ++j) {
            sl += v[j] * attn_l[h * OUT_F + f + j];
            sr += v[j] * attn_r[h * OUT_F + f + j];
        }
    }
    el[tid] = sl;
    er[tid] = sr;
}

// ---------------- CSR build: histogram
__global__ void hist_kernel(const int* __restrict__ dst, int* __restrict__ cnt) {
    const int e = blockIdx.x * blockDim.x + threadIdx.x;
    if (e >= N_EDGES) return;
    atomicAdd(cnt + dst[e], 1);
}

// ---------------- CSR build: 3-step exclusive scan
__global__ __launch_bounds__(SCAN_B) void scan1_kernel(const int* __restrict__ cnt,
                                                       int* __restrict__ offs,
                                                       int* __restrict__ bsum) {
    __shared__ int sh[SCAN_B];
    const int t = threadIdx.x;
    const int i = blockIdx.x * SCAN_B + t;
    const int v = (i < N_NODES) ? cnt[i] : 0;
    sh[t] = v;
    __syncthreads();
    for (int off = 1; off < SCAN_B; off <<= 1) {
        const int x = (t >= off) ? sh[t - off] : 0;
        __syncthreads();
        sh[t] += x;
        __syncthreads();
    }
    if (i < N_NODES) offs[i] = sh[t] - v;
    if (t == SCAN_B - 1) bsum[blockIdx.x] = sh[t];
}

__global__ __launch_bounds__(256) void scan2_kernel(int* __restrict__ bsum) {
    __shared__ int sh[256];
    const int t = threadIdx.x;
    const int v = (t < NB1) ? bsum[t] : 0;
    sh[t] = v;
    __syncthreads();
    for (int off = 1; off < 256; off <<= 1) {
        const int x = (t >= off) ? sh[t - off] : 0;
        __syncthreads();
        sh[t] += x;
        __syncthreads();
    }
    if (t < NB1) bsum[t] = sh[t] - v;
}

__global__ __launch_bounds__(SCAN_B) void scan3_kernel(int* __restrict__ offs,
                                                       const int* __restrict__ bsum) {
    const int i = blockIdx.x * SCAN_B + threadIdx.x;
    if (i < N_NODES) offs[i] += bsum[blockIdx.x];
}

// ---------------- scatter: one 16B record {src, 4 x f16 ewdot} per edge
__global__ void scatter_kernel(const float* __restrict__ e_w,
                               const int* __restrict__ src, const int* __restrict__ dst,
                               const float* __restrict__ attn_ew,
                               const int* __restrict__ offs, int* __restrict__ cursor,
                               int4* __restrict__ recs) {
    const int e = blockIdx.x * blockDim.x + threadIdx.x;
    if (e >= N_EDGES) return;
    const int s = src[e], d = dst[e];
    const float4 w01 = *(const float4*)(e_w + (size_t)e * 8);
    const float4 w23 = *(const float4*)(e_w + (size_t)e * 8 + 4);
    const float4 a01 = *(const float4*)(attn_ew);
    const float4 a23 = *(const float4*)(attn_ew + 4);
    const float d0 = w01.x * a01.x + w01.y * a01.y;
    const float d1 = w01.z * a01.z + w01.w * a01.w;
    const float d2 = w23.x * a23.x + w23.y * a23.y;
    const float d3 = w23.z * a23.z + w23.w * a23.w;
    const int pos  = atomicAdd(cursor + d, 1);
    const int slot = offs[d] + pos;
    int4 r;
    r.x = s;
    r.y = (int)pack_h2(d0, d1);
    r.z = (int)pack_h2(d2, d3);
    r.w = 0;
    recs[slot] = r;
}

// ---------------- aggregation: 1 wave/node, exp hoisted to once per (edge,head)
#define CH 64
__global__ __launch_bounds__(64) void agg_kernel(const int* __restrict__ offs,
                                                 const int* __restrict__ cnt,
                                                 const int4* __restrict__ recs,
                                                 const float* __restrict__ el,
                                                 const float* __restrict__ er,
                                                 const ushort* __restrict__ fsb,
                                                 float* __restrict__ out) {
    __shared__ float sh_log[CH * 4];
    __shared__ float sh_w[CH * 4];
    __shared__ int   sh_src[CH];
    const int n  = blockIdx.x;
    const int t  = threadIdx.x;       // 0..63; feats 2t, 2t+1; head h = t>>4
    const int h  = t >> 4;
    const int jl = t & 15;            // lane within head group
    const int beg = offs[n];
    const int deg = cnt[n];
    const float4 ern = *(const float4*)(er + (size_t)n * 4);

    float m = -1e30f, den = 0.f;
    float accx = 0.f, accy = 0.f;

    for (int c = 0; c < deg; c += CH) {
        const int cn = min(CH, deg - c);
        if (t < cn) {
            const int4 r = recs[beg + c + t];
            const int s = r.x;
            const float4 l4 = *(const float4*)(el + (size_t)s * 4);
            float v0 = l4.x + ern.x + unpack_lo((unsigned)r.y);
            float v1 = l4.y + ern.y + unpack_hi((unsigned)r.y);
            float v2 = l4.z + ern.z + unpack_lo((unsigned)r.z);
            float v3 = l4.w + ern.w + unpack_hi((unsigned)r.z);
            v0 = v0 > 0.f ? v0 : NEG_SLOPE * v0;
            v1 = v1 > 0.f ? v1 : NEG_SLOPE * v1;
            v2 = v2 > 0.f ? v2 : NEG_SLOPE * v2;
            v3 = v3 > 0.f ? v3 : NEG_SLOPE * v3;
            *(float4*)&sh_log[t * 4] = make_float4(v0, v1, v2, v3);
            sh_src[t] = s;
        }
        __syncthreads();
        // per-head chunk max: strided + 16-lane butterfly
        float cm = m;
        for (int j = jl; j < cn; j += 16) cm = fmaxf(cm, sh_log[j * 4 + h]);
#pragma unroll
        for (int mask = 1; mask <= 8; mask <<= 1)
            cm = fmaxf(cm, __shfl_xor(cm, mask));
        const float scale = __expf(m - cm);   // first chunk: exp(-huge)=0
        accx *= scale; accy *= scale; den *= scale;
        m = cm;
        // exp once per (edge, head)
        for (int j = jl; j < cn; j += 16)
            sh_w[j * 4 + h] = __expf(sh_log[j * 4 + h] - m);
        __syncthreads();
#pragma unroll 4
        for (int j = 0; j < cn; ++j) {
            const float wgt = sh_w[j * 4 + h];
            const int s = sh_src[j];
            const ushort2 u = *(const ushort2*)(fsb + (size_t)s * HF + 2 * t);
            accx += wgt * b2f(u.x);
            accy += wgt * b2f(u.y);
            den  += wgt;
        }
        __syncthreads();
    }
    const float inv = (deg > 0) ? 1.f / den : 0.f;
    float rx = accx * inv, ry = accy * inv;
    rx = rx > 0.f ? rx : expm1f(rx);
    ry = ry > 0.f ? ry : expm1f(ry);
    *(float2*)(out + (size_t)n * HF + 2 * t) = make_float2(rx, ry);
}

extern "C" void kernel_launch(void* const* d_in, const int* in_sizes, int n_in,
                              void* d_out, int out_size, void* d_ws, size_t ws_size,
                              hipStream_t stream) {
    const float* feat    = (const float*)d_in[0];
    const float* e_w     = (const float*)d_in[1];
    const int*   src     = (const int*)d_in[2];
    const int*   dst     = (const int*)d_in[3];
    const float* W       = (const float*)d_in[4];
    const float* attn_l  = (const float*)d_in[5];
    const float* attn_r  = (const float*)d_in[6];
    const float* attn_ew = (const float*)d_in[7];
    float* out = (float*)d_out;

    ushort* fsb    = (ushort*)d_ws;                          // 25.6 MB bf16 feat_src
    float*  el     = (float*)(fsb + (size_t)N_NODES * HF);   // 1.6 MB
    float*  er     = el + (size_t)N_NODES * HEADS;           // 1.6 MB
    int*    counts = (int*)(er + (size_t)N_NODES * HEADS);   // 0.4 MB
    int*    offs   = counts + N_NODES;                       // 0.4 MB
    int*    cursor = offs + N_NODES;                         // 0.4 MB
    int*    bsum   = cursor + N_NODES;                       // 4 KB
    int4*   recs   = (int4*)(bsum + 1024);                   // 25.6 MB

    hipMemsetAsync(counts, 0, N_NODES * sizeof(int), stream);
    hipMemsetAsync(cursor, 0, N_NODES * sizeof(int), stream);

    gemm_mfma<<<(N_NODES + 63) / 64, 256, 0, stream>>>(feat, W, fsb);
    elr_kernel<<<(N_NODES * HEADS + 255) / 256, 256, 0, stream>>>(fsb, attn_l, attn_r, el, er);
    hist_kernel<<<(N_EDGES + 255) / 256, 256, 0, stream>>>(dst, counts);
    scan1_kernel<<<NB1, SCAN_B, 0, stream>>>(counts, offs, bsum);
    scan2_kernel<<<1, 256, 0, stream>>>(bsum);
    scan3_kernel<<<NB1, SCAN_B, 0, stream>>>(offs, bsum);
    scatter_kernel<<<(N_EDGES + 255) / 256, 256, 0, stream>>>(e_w, src, dst, attn_ew,
                                                              offs, cursor, recs);
    agg_kernel<<<N_NODES, 64, 0, stream>>>(offs, counts, recs, el, er, fsb, out);
}